// Round 4
// baseline (52.882 us; speedup 1.0000x reference)
//
#include <hip/hip_runtime.h>

// sigmoid( (1/L) * sum_{l<len_b} dot(emb_table[tokens[b,l]], W) + bias )
// HBM-bound gather: ~sum(lengths)*4000B ~= 262 MB of row reads.
// v4: chunk-major block ordering (uniform work per scheduling round),
//     token prefetch before row loop, 1-wave finalize.

constexpr int B_ = 64;
constexpr int L_ = 2048;
constexpr int P_ = 1000;           // floats per row (250 float4, rows 16B-aligned)
constexpr int CPS = 128;           // chunks (blocks) per sequence
constexpr int BDIM = 256;          // 4 waves
constexpr int WAVES = BDIM / 64;
constexpr int SLOTS = CPS * WAVES;     // 512 wave-slots per sequence, stride 512
constexpr int NBLK = B_ * CPS;         // 8192 blocks

__global__ __launch_bounds__(BDIM) void pool_dot_kernel(
    const int* __restrict__ tokens,    // [B_, L_]
    const int* __restrict__ lengths,   // [B_]
    const float* __restrict__ emb,     // [VOCAB, P_]
    const float* __restrict__ W,       // [P_]
    float* __restrict__ partial)       // [NBLK], index = chunk*64 + seq
{
    const int blk   = blockIdx.x;
    const int seq   = blk & (B_ - 1);  // chunk-major: consecutive blocks sweep seqs
    const int chunk = blk >> 6;        // [0, CPS)
    const int lane  = threadIdx.x & 63;
    const int wave  = threadIdx.x >> 6;

    const int len = (int)lengths[seq];
    __shared__ float red[WAVES];

    float accl = 0.0f;
    const int s0 = chunk + CPS * wave;                            // [0, 512)
    const int nm = (s0 < len) ? (((len - 1 - s0) >> 9) + 1) : 0;  // stride 512, <=4

    if (nm > 0) {
        // W fragment in registers: lane covers float4 indices lane + 64k, k=0..3
        const float4* W4 = (const float4*)W;
        float4 wf[4];
        #pragma unroll
        for (int k = 0; k < 4; ++k) {
            const int j = lane + 64 * k;
            if (j < P_ / 4) wf[k] = W4[j];
            else            wf[k] = make_float4(0.f, 0.f, 0.f, 0.f);
        }
        // Prefetch all row indices (breaks token->rowload dependency chain)
        const int* trow = tokens + seq * L_;
        int row[4];
        #pragma unroll
        for (int m = 0; m < 4; ++m) {
            const int t = s0 + (m << 9);
            row[m] = trow[(m < nm) ? t : s0];
        }
        #pragma unroll 4
        for (int m = 0; m < nm; ++m) {
            const float4* e4 = (const float4*)(emb + (size_t)row[m] * P_);
            #pragma unroll
            for (int k = 0; k < 4; ++k) {
                const int j = lane + 64 * k;
                if (j < P_ / 4) {
                    const float4 e = e4[j];
                    accl = fmaf(e.x, wf[k].x, accl);
                    accl = fmaf(e.y, wf[k].y, accl);
                    accl = fmaf(e.z, wf[k].z, accl);
                    accl = fmaf(e.w, wf[k].w, accl);
                }
            }
        }
    }

    // wave reduction (64 lanes)
    #pragma unroll
    for (int off = 32; off > 0; off >>= 1)
        accl += __shfl_down(accl, off, 64);
    if (lane == 0) red[wave] = accl;
    __syncthreads();
    if (threadIdx.x == 0) {
        float s = 0.0f;
        #pragma unroll
        for (int w = 0; w < WAVES; ++w) s += red[w];
        partial[blk] = s;   // every block writes -> no ws zeroing needed
    }
}

// One wave: thread s sums partial[c*64 + s] over c (fully coalesced 256B rows).
__global__ __launch_bounds__(64) void finalize_kernel(
    const float* __restrict__ partial, // [NBLK], index = chunk*64 + seq
    const float* __restrict__ bias,    // [1]
    float* __restrict__ out)           // [B_]
{
    const int s = threadIdx.x;         // seq
    float acc = 0.0f;
    #pragma unroll 16
    for (int c = 0; c < CPS; ++c)
        acc += partial[c * B_ + s];
    const float v = acc * (1.0f / (float)L_) + bias[0];
    out[s] = 1.0f / (1.0f + expf(-v));
}

extern "C" void kernel_launch(void* const* d_in, const int* in_sizes, int n_in,
                              void* d_out, int out_size, void* d_ws, size_t ws_size,
                              hipStream_t stream) {
    const int*   tokens  = (const int*)d_in[0];
    const int*   lengths = (const int*)d_in[1];
    const float* emb     = (const float*)d_in[2];
    const float* W       = (const float*)d_in[3];
    const float* bias    = (const float*)d_in[4];
    float* out     = (float*)d_out;
    float* partial = (float*)d_ws;   // NBLK floats = 32 KB

    pool_dot_kernel<<<NBLK, BDIM, 0, stream>>>(tokens, lengths, emb, W, partial);
    finalize_kernel<<<1, 64, 0, stream>>>(partial, bias, out);
}

// Round 5
// 46.450 us; speedup vs baseline: 1.1385x; 1.1385x over previous
//
#include <hip/hip_runtime.h>

// sigmoid( (1/L) * sum_{l<len_b} dot(emb_table[tokens[b,l]], W) + bias )
// HBM-bound gather: ~sum(lengths)*4000B ~= 262 MB of row reads.
// v5 == v3 exactly (revert of v4's chunk-major ordering + prefetch + 1-wave
// finalize, which regressed 47.0 -> 52.9 us). Isolation / noise measurement.

constexpr int B_ = 64;
constexpr int L_ = 2048;
constexpr int P_ = 1000;           // floats per row (250 float4, rows 16B-aligned)
constexpr int CPS = 128;           // chunks (blocks) per sequence
constexpr int BDIM = 256;          // 4 waves
constexpr int WAVES = BDIM / 64;
constexpr int NBLK = B_ * CPS;     // 8192 blocks

__global__ __launch_bounds__(BDIM) void pool_dot_kernel(
    const int* __restrict__ tokens,    // [B_, L_]
    const int* __restrict__ lengths,   // [B_]
    const float* __restrict__ emb,     // [VOCAB, P_]
    const float* __restrict__ W,       // [P_]
    float* __restrict__ partial)       // [NBLK]
{
    const int blk   = blockIdx.x;
    const int seq   = blk >> 7;        // seq-major: co-resident blocks share seq
    const int chunk = blk & (CPS - 1);
    const int lane  = threadIdx.x & 63;
    const int wave  = threadIdx.x >> 6;

    const int len = (int)lengths[seq];
    __shared__ float red[WAVES];

    float accl = 0.0f;
    const int s0 = chunk + CPS * wave;                            // [0, 512)
    const int nm = (s0 < len) ? (((len - 1 - s0) >> 9) + 1) : 0;  // stride 512, <=4

    if (nm > 0) {
        // W fragment in registers: lane covers float4 indices lane + 64k, k=0..3
        const float4* W4 = (const float4*)W;
        float4 wf[4];
        #pragma unroll
        for (int k = 0; k < 4; ++k) {
            const int j = lane + 64 * k;
            if (j < P_ / 4) wf[k] = W4[j];
            else            wf[k] = make_float4(0.f, 0.f, 0.f, 0.f);
        }
        const int* trow = tokens + seq * L_;
        #pragma unroll 4
        for (int m = 0; m < nm; ++m) {
            const int t   = s0 + (m << 9);
            const int row = trow[t];                       // wave-uniform load
            const float4* e4 = (const float4*)(emb + (size_t)row * P_);
            #pragma unroll
            for (int k = 0; k < 4; ++k) {
                const int j = lane + 64 * k;
                if (j < P_ / 4) {
                    const float4 e = e4[j];
                    accl = fmaf(e.x, wf[k].x, accl);
                    accl = fmaf(e.y, wf[k].y, accl);
                    accl = fmaf(e.z, wf[k].z, accl);
                    accl = fmaf(e.w, wf[k].w, accl);
                }
            }
        }
    }

    // wave reduction (64 lanes)
    #pragma unroll
    for (int off = 32; off > 0; off >>= 1)
        accl += __shfl_down(accl, off, 64);
    if (lane == 0) red[wave] = accl;
    __syncthreads();
    if (threadIdx.x == 0) {
        float s = 0.0f;
        #pragma unroll
        for (int w = 0; w < WAVES; ++w) s += red[w];
        partial[blk] = s;   // every block writes -> no ws zeroing needed
    }
}

// Single block, 256 threads: 4 threads per sequence, each sums 32 partials.
__global__ __launch_bounds__(256) void finalize_kernel(
    const float* __restrict__ partial, // [NBLK] = [B_ * CPS]
    const float* __restrict__ bias,    // [1]
    float* __restrict__ out)           // [B_]
{
    const int i   = threadIdx.x;
    const int seq = i >> 2;
    const int q   = i & 3;
    float s = 0.0f;
    #pragma unroll
    for (int j = 0; j < CPS / 4; ++j)
        s += partial[seq * CPS + q + 4 * j];
    s += __shfl_xor(s, 1, 64);
    s += __shfl_xor(s, 2, 64);
    if (q == 0) {
        const float v = s * (1.0f / (float)L_) + bias[0];
        out[seq] = 1.0f / (1.0f + expf(-v));
    }
}

extern "C" void kernel_launch(void* const* d_in, const int* in_sizes, int n_in,
                              void* d_out, int out_size, void* d_ws, size_t ws_size,
                              hipStream_t stream) {
    const int*   tokens  = (const int*)d_in[0];
    const int*   lengths = (const int*)d_in[1];
    const float* emb     = (const float*)d_in[2];
    const float* W       = (const float*)d_in[3];
    const float* bias    = (const float*)d_in[4];
    float* out     = (float*)d_out;
    float* partial = (float*)d_ws;   // NBLK floats = 32 KB

    pool_dot_kernel<<<NBLK, BDIM, 0, stream>>>(tokens, lengths, emb, W, partial);
    finalize_kernel<<<1, 256, 0, stream>>>(partial, bias, out);
}